// Round 12
// baseline (354.973 us; speedup 1.0000x reference)
//
#include <hip/hip_runtime.h>

#define N_NODES 250000
#define N_EDGES 4000000
#define N_GRAPHS 512
#define NEG 0.01f
#define BINB 9
#define WIN 512
#define NBINS 489            // ceil(250000 / 512)
#define NSUB (NBINS * 4)     // dst-bin x src-quarter
#define CAPQ 2560            // per-sub-bin capacity: mean ~2045 + 11 sigma
#define PART_EPB 8192
#define PART_BLOCKS 489      // 489 * 8192 >= N_EDGES

__device__ __forceinline__ float lrelu(float v) { return v > 0.0f ? v : NEG * v; }
__device__ __forceinline__ unsigned f2b(float f) {
    unsigned u = __float_as_uint(f);
    unsigned r = ((u >> 16) & 1u) + 0x7FFFu;
    return (u + r) >> 16;
}
__device__ __forceinline__ unsigned pk(float a, float b) { return f2b(a) | (f2b(b) << 16); }
__device__ __forceinline__ float blo(unsigned p) { return __uint_as_float(p << 16); }
__device__ __forceinline__ float bhi(unsigned p) { return __uint_as_float(p & 0xFFFF0000u); }

// ---- Pack x into x16b (16 bf16 = 32 B rows); block 0 zeroes qcnt -------
__global__ void pack_x(const float* __restrict__ x, unsigned* __restrict__ x16b,
                       int* __restrict__ qcnt) {
    if (blockIdx.x == 0) {
        for (int i = threadIdx.x; i < NSUB; i += 256) qcnt[i] = 0;
    }
    int tid = blockIdx.x * blockDim.x + threadIdx.x;
    if (tid >= N_NODES * 8) return;
    int n = tid >> 3, d2 = tid & 7;
    int a = d2 * 2, b = a + 1;
    float va = (a < 13) ? x[n * 13 + a] : 0.0f;
    float vb = (b < 13) ? x[n * 13 + b] : 0.0f;
    x16b[tid] = pk(va, vb);
}

// ---- Edge binning with in-LDS sort by sub-bin (dense run writes) -------
__global__ __launch_bounds__(1024) void partition_k(const int* __restrict__ src,
                                                    const int* __restrict__ dst,
                                                    int* __restrict__ qcnt,
                                                    unsigned* __restrict__ binned) {
    __shared__ int hist[NSUB];            // later reused as scatter cursor
    __shared__ int loff[NSUB];
    __shared__ int base[NSUB];
    __shared__ unsigned ebuf[PART_EPB];
    __shared__ unsigned short subid[PART_EPB];
    __shared__ int wsum[16];
    int t = threadIdx.x;
    for (int i = t; i < NSUB; i += 1024) hist[i] = 0;
    __syncthreads();
    unsigned e0 = blockIdx.x * PART_EPB;
    int m = min((int)PART_EPB, (int)(N_EDGES - e0));
    for (int i = t; i < m; i += 1024) {
        unsigned e = e0 + i;
        int s = ((dst[e] >> BINB) << 2) | (src[e] >> 16);
        atomicAdd(&hist[s], 1);
    }
    __syncthreads();
    // exclusive scan over 1956 counters via 978 pairs + wave shuffles
    int p = 0, s0 = 0, incl = 0;
    if (t < NSUB / 2) { s0 = hist[2 * t]; p = s0 + hist[2 * t + 1]; }
    incl = p;
#pragma unroll
    for (int d = 1; d < 64; d <<= 1) {
        int u = __shfl_up(incl, d, 64);
        if ((t & 63) >= d) incl += u;
    }
    if ((t & 63) == 63) wsum[t >> 6] = incl;
    __syncthreads();
    if (t == 0) {
        int r = 0;
#pragma unroll
        for (int i = 0; i < 16; i++) { int s = wsum[i]; wsum[i] = r; r += s; }
    }
    __syncthreads();
    if (t < NSUB / 2) {
        int ex = incl + wsum[t >> 6] - p;
        loff[2 * t] = ex;
        loff[2 * t + 1] = ex + s0;
    }
    __syncthreads();
    // reserve global chunks (uses hist), then hist becomes cursor = loff
    for (int i = t; i < NSUB; i += 1024) {
        int h = hist[i];
        base[i] = (h > 0) ? atomicAdd(&qcnt[i], h) : 0;
    }
    __syncthreads();
    for (int i = t; i < NSUB; i += 1024) hist[i] = loff[i];
    __syncthreads();
    // pass 2: re-read edges, scatter into LDS sorted-by-sub order
    for (int i = t; i < m; i += 1024) {
        unsigned e = e0 + i;
        int d = dst[e], sv = src[e];
        int s = ((d >> BINB) << 2) | (sv >> 16);
        int pos = atomicAdd(&hist[s], 1);
        ebuf[pos] = ((unsigned)(d & (WIN - 1)) << 18) | (unsigned)sv;
        subid[pos] = (unsigned short)s;
    }
    __syncthreads();
    // write-out: consecutive lanes hit consecutive addresses of each run
    for (int j = t; j < m; j += 1024) {
        int s = subid[j];
        binned[(size_t)s * CAPQ + base[s] + (j - loff[s])] = ebuf[j];
    }
}

// ---- Sort by dst + layer-1 aggregation + fused node linear 1 -----------
__global__ __launch_bounds__(1024) void sortagg_k(const unsigned* __restrict__ x16b,
                                                  unsigned* __restrict__ binned,
                                                  const int* __restrict__ qcnt,
                                                  int* __restrict__ offs,
                                                  float* __restrict__ cntf,
                                                  const float* __restrict__ W1l,
                                                  const float* __restrict__ b1,
                                                  const float* __restrict__ W1r,
                                                  const float* __restrict__ W2l,
                                                  const float* __restrict__ W2r,
                                                  unsigned* __restrict__ y2b,
                                                  float* __restrict__ z2) {
    __shared__ __align__(16) unsigned char sm[35584];
    unsigned* stg = (unsigned*)sm;                 // CAPQ
    unsigned* srt = stg + CAPQ;                    // CAPQ
    int* hist = (int*)(srt + CAPQ);                // WIN
    int* cur = hist + WIN;                         // WIN
    int* wsum = cur + WIN;                         // 8
    float* sagg = (float*)sm;                      // phase B: 8192 floats
    float* swt = sagg + 8192;                      // phase B: 688 floats
    int t = threadIdx.x;
    int bin = blockIdx.x;
    int f = t & (WIN - 1), l = t >> 9;
    int lane = t & 63, wv = t >> 6;
    float a0 = 0, a1 = 0, a2 = 0, a3 = 0, a4 = 0, a5 = 0, a6 = 0, a7 = 0;
    int deg = 0;
    for (int q = 0; q < 4; q++) {
        int sub = (bin << 2) | q;
        int cnt = qcnt[sub];
        unsigned* bp = binned + (size_t)sub * CAPQ;
        if (t < WIN) hist[t] = 0;
        __syncthreads();
        for (int i = t; i < cnt; i += 1024) {
            unsigned w = bp[i];
            stg[i] = w;
            atomicAdd(&hist[w >> 18], 1);
        }
        __syncthreads();
        int v = (t < WIN) ? hist[t] : 0;
#pragma unroll
        for (int d = 1; d < 64; d <<= 1) {
            int u = __shfl_up(v, d, 64);
            if (lane >= d) v += u;
        }
        if (t < WIN && lane == 63) wsum[wv] = v;
        __syncthreads();
        if (t == 0) {
            int r = 0;
#pragma unroll
            for (int i = 0; i < 8; i++) { int s = wsum[i]; wsum[i] = r; r += s; }
        }
        __syncthreads();
        if (t < WIN) {
            int incl = v + wsum[wv];
            int ex = incl - hist[t];
            cur[t] = ex;
            offs[(size_t)sub * 513 + t] = ex;
            deg += hist[t];
        }
        if (t == 0) offs[(size_t)sub * 513 + WIN] = cnt;
        __syncthreads();
        for (int i = t; i < cnt; i += 1024) {
            unsigned w = stg[i];
            int pos = atomicAdd(&cur[w >> 18], 1);
            srt[pos] = w;
        }
        __syncthreads();
        for (int i = t; i < cnt; i += 1024) bp[i] = srt[i];
        int e_ = cur[f];
        int s_ = e_ - hist[f];
        int k = s_;
        for (; k + 4 <= e_; k += 4) {
            unsigned w0 = srt[k], w1 = srt[k + 1], w2 = srt[k + 2], w3 = srt[k + 3];
            uint4 v0 = *(const uint4*)&x16b[(size_t)(w0 & 0x3FFFFu) * 8u + (unsigned)(l * 4)];
            uint4 v1 = *(const uint4*)&x16b[(size_t)(w1 & 0x3FFFFu) * 8u + (unsigned)(l * 4)];
            uint4 v2 = *(const uint4*)&x16b[(size_t)(w2 & 0x3FFFFu) * 8u + (unsigned)(l * 4)];
            uint4 v3 = *(const uint4*)&x16b[(size_t)(w3 & 0x3FFFFu) * 8u + (unsigned)(l * 4)];
            a0 += blo(v0.x) + blo(v1.x) + blo(v2.x) + blo(v3.x);
            a1 += bhi(v0.x) + bhi(v1.x) + bhi(v2.x) + bhi(v3.x);
            a2 += blo(v0.y) + blo(v1.y) + blo(v2.y) + blo(v3.y);
            a3 += bhi(v0.y) + bhi(v1.y) + bhi(v2.y) + bhi(v3.y);
            a4 += blo(v0.z) + blo(v1.z) + blo(v2.z) + blo(v3.z);
            a5 += bhi(v0.z) + bhi(v1.z) + bhi(v2.z) + bhi(v3.z);
            a6 += blo(v0.w) + blo(v1.w) + blo(v2.w) + blo(v3.w);
            a7 += bhi(v0.w) + bhi(v1.w) + bhi(v2.w) + bhi(v3.w);
        }
        for (; k < e_; k++) {
            unsigned w = srt[k];
            uint4 v4 = *(const uint4*)&x16b[(size_t)(w & 0x3FFFFu) * 8u + (unsigned)(l * 4)];
            a0 += blo(v4.x); a1 += bhi(v4.x); a2 += blo(v4.y); a3 += bhi(v4.y);
            a4 += blo(v4.z); a5 += bhi(v4.z); a6 += blo(v4.w); a7 += bhi(v4.w);
        }
        __syncthreads();
    }
    // ---- phase B: fused node linear 1 (ex-fused1) ----
    {
        float av[8] = {a0, a1, a2, a3, a4, a5, a6, a7};
#pragma unroll
        for (int i = 0; i < 8; i++) sagg[(f << 4) + (l << 3) + i] = av[i];
    }
    for (int i = t; i < 688; i += 1024) {
        float w;
        if (i < 208) w = W1l[i];
        else if (i < 416) w = W1r[i - 208];
        else if (i < 432) w = b1[i - 416];
        else if (i < 560) w = W2l[i - 432];
        else w = W2r[i - 560];
        swt[i] = w;
    }
    __syncthreads();
    if (t < WIN) {
        int g = (bin << BINB) + t;
        if (g < N_NODES) {
            const float* sWl = swt;
            const float* sWr = swt + 208;
            const float* sbb = swt + 416;
            const float* sA = swt + 432;
            const float* sB = swt + 560;
            float inv = 1.0f / (float)max(deg, 1);
            float a[13], xv[13];
#pragma unroll
            for (int i = 0; i < 13; i++) a[i] = sagg[(t << 4) + i] * inv;
#pragma unroll
            for (int i2 = 0; i2 < 7; i2++) {
                unsigned u = x16b[(size_t)g * 8 + i2];
                xv[2 * i2] = blo(u);
                if (2 * i2 + 1 < 13) xv[2 * i2 + 1] = bhi(u);
            }
            float h[16];
#pragma unroll
            for (int o = 0; o < 16; o++) {
                float acc = sbb[o];
#pragma unroll
                for (int i = 0; i < 13; i++) acc += a[i] * sWl[i * 16 + o] + xv[i] * sWr[i * 16 + o];
                h[o] = lrelu(acc);
            }
            float ya[8], z[8];
#pragma unroll
            for (int o2 = 0; o2 < 8; o2++) {
                float y = 0.0f, za = 0.0f;
#pragma unroll
                for (int o = 0; o < 16; o++) { y += h[o] * sA[o * 8 + o2]; za += h[o] * sB[o * 8 + o2]; }
                ya[o2] = y; z[o2] = za;
            }
            uint4 o4;
            o4.x = pk(ya[0], ya[1]); o4.y = pk(ya[2], ya[3]);
            o4.z = pk(ya[4], ya[5]); o4.w = pk(ya[6], ya[7]);
            *(uint4*)&y2b[(size_t)g * 4u] = o4;
            *(float4*)&z2[(size_t)g * 8] = make_float4(z[0], z[1], z[2], z[3]);
            *(float4*)&z2[(size_t)g * 8 + 4] = make_float4(z[4], z[5], z[6], z[7]);
            cntf[g] = (float)deg;
        }
    }
}

// ---- Layer-2 gather + fused epilogue: h2 (in z2), y3b ------------------
__global__ __launch_bounds__(256) void agg8f_k(const unsigned* __restrict__ y2b,
                                               const unsigned* __restrict__ binned,
                                               const int* __restrict__ offs,
                                               const float* __restrict__ cntf,
                                               const float* __restrict__ b2,
                                               const float* __restrict__ W3l,
                                               float* __restrict__ z2h2,
                                               unsigned* __restrict__ y3b,
                                               float* __restrict__ pool) {
    __shared__ float sb[8], sW3[32];
    if (blockIdx.x == 0) {
        for (int i = threadIdx.x; i < N_GRAPHS * 5; i += 256) pool[i] = 0.0f;
    }
    if (threadIdx.x < 8) sb[threadIdx.x] = b2[threadIdx.x];
    if (threadIdx.x < 32) sW3[threadIdx.x] = W3l[threadIdx.x];
    __syncthreads();
    int g = blockIdx.x * 256 + threadIdx.x;
    if (g >= N_NODES) return;
    int bin = g >> BINB, f = g & (WIN - 1);
    float a0 = 0, a1 = 0, a2 = 0, a3 = 0, a4 = 0, a5 = 0, a6 = 0, a7 = 0;
#pragma unroll
    for (int q = 0; q < 4; q++) {
        int sub = (bin << 2) | q;
        const int* o = offs + (size_t)sub * 513;
        int s = o[f], e = o[f + 1];
        const unsigned* bp = binned + (size_t)sub * CAPQ;
        int k = s;
        for (; k + 4 <= e; k += 4) {
            unsigned w0 = bp[k], w1 = bp[k + 1], w2 = bp[k + 2], w3 = bp[k + 3];
            uint4 v0 = *(const uint4*)&y2b[(size_t)(w0 & 0x3FFFFu) * 4u];
            uint4 v1 = *(const uint4*)&y2b[(size_t)(w1 & 0x3FFFFu) * 4u];
            uint4 v2 = *(const uint4*)&y2b[(size_t)(w2 & 0x3FFFFu) * 4u];
            uint4 v3 = *(const uint4*)&y2b[(size_t)(w3 & 0x3FFFFu) * 4u];
            a0 += blo(v0.x) + blo(v1.x) + blo(v2.x) + blo(v3.x);
            a1 += bhi(v0.x) + bhi(v1.x) + bhi(v2.x) + bhi(v3.x);
            a2 += blo(v0.y) + blo(v1.y) + blo(v2.y) + blo(v3.y);
            a3 += bhi(v0.y) + bhi(v1.y) + bhi(v2.y) + bhi(v3.y);
            a4 += blo(v0.z) + blo(v1.z) + blo(v2.z) + blo(v3.z);
            a5 += bhi(v0.z) + bhi(v1.z) + bhi(v2.z) + bhi(v3.z);
            a6 += blo(v0.w) + blo(v1.w) + blo(v2.w) + blo(v3.w);
            a7 += bhi(v0.w) + bhi(v1.w) + bhi(v2.w) + bhi(v3.w);
        }
        for (; k < e; k++) {
            uint4 v = *(const uint4*)&y2b[(size_t)(bp[k] & 0x3FFFFu) * 4u];
            a0 += blo(v.x); a1 += bhi(v.x); a2 += blo(v.y); a3 += bhi(v.y);
            a4 += blo(v.z); a5 += bhi(v.z); a6 += blo(v.w); a7 += bhi(v.w);
        }
    }
    float inv = 1.0f / fmaxf(cntf[g], 1.0f);
    float h2v[8];
    float s8[8] = {a0, a1, a2, a3, a4, a5, a6, a7};
#pragma unroll
    for (int j = 0; j < 8; j++) {
        float v = s8[j] * inv + sb[j] + z2h2[(size_t)g * 8 + j];
        h2v[j] = lrelu(v);
        z2h2[(size_t)g * 8 + j] = h2v[j];
    }
    float y[4];
#pragma unroll
    for (int k = 0; k < 4; k++) {
        float acc = 0.0f;
#pragma unroll
        for (int j = 0; j < 8; j++) acc += h2v[j] * sW3[j * 4 + k];
        y[k] = acc;
    }
    uint2 out;
    out.x = pk(y[0], y[1]); out.y = pk(y[2], y[3]);
    *(uint2*)&y3b[(size_t)g * 2u] = out;
}

// ---- Layer-3 gather + fused epilogue + pooling -------------------------
__global__ __launch_bounds__(256) void agg4pool_k(const unsigned* __restrict__ y3b,
                                                  const unsigned* __restrict__ binned,
                                                  const int* __restrict__ offs,
                                                  const float* __restrict__ cntf,
                                                  const float* __restrict__ h2,
                                                  const float* __restrict__ W3r,
                                                  const float* __restrict__ b3,
                                                  const int* __restrict__ batch,
                                                  float* __restrict__ pool,
                                                  float* __restrict__ gcnt) {
    __shared__ float sW[32], sb[4];
    __shared__ float lp[16][4];
    __shared__ float lc[16];
    __shared__ int sbase;
    if (threadIdx.x < 32) sW[threadIdx.x] = W3r[threadIdx.x];
    if (threadIdx.x < 4) sb[threadIdx.x] = b3[threadIdx.x];
    if (threadIdx.x < 16) {
        lc[threadIdx.x] = 0.0f;
        for (int k = 0; k < 4; k++) lp[threadIdx.x][k] = 0.0f;
    }
    int n0 = blockIdx.x * 256;
    if (threadIdx.x == 0) sbase = batch[n0 < N_NODES ? n0 : N_NODES - 1];
    __syncthreads();
    int g = n0 + threadIdx.x;
    if (g < N_NODES) {
        int bin = g >> BINB, f = g & (WIN - 1);
        float a0 = 0, a1 = 0, a2 = 0, a3 = 0;
#pragma unroll
        for (int q = 0; q < 4; q++) {
            int sub = (bin << 2) | q;
            const int* o = offs + (size_t)sub * 513;
            int s = o[f], e = o[f + 1];
            const unsigned* bp = binned + (size_t)sub * CAPQ;
            int k = s;
            for (; k + 4 <= e; k += 4) {
                unsigned w0 = bp[k], w1 = bp[k + 1], w2 = bp[k + 2], w3 = bp[k + 3];
                uint2 v0 = *(const uint2*)&y3b[(size_t)(w0 & 0x3FFFFu) * 2u];
                uint2 v1 = *(const uint2*)&y3b[(size_t)(w1 & 0x3FFFFu) * 2u];
                uint2 v2 = *(const uint2*)&y3b[(size_t)(w2 & 0x3FFFFu) * 2u];
                uint2 v3 = *(const uint2*)&y3b[(size_t)(w3 & 0x3FFFFu) * 2u];
                a0 += blo(v0.x) + blo(v1.x) + blo(v2.x) + blo(v3.x);
                a1 += bhi(v0.x) + bhi(v1.x) + bhi(v2.x) + bhi(v3.x);
                a2 += blo(v0.y) + blo(v1.y) + blo(v2.y) + blo(v3.y);
                a3 += bhi(v0.y) + bhi(v1.y) + bhi(v2.y) + bhi(v3.y);
            }
            for (; k < e; k++) {
                uint2 v = *(const uint2*)&y3b[(size_t)(bp[k] & 0x3FFFFu) * 2u];
                a0 += blo(v.x); a1 += bhi(v.x); a2 += blo(v.y); a3 += bhi(v.y);
            }
        }
        float inv = 1.0f / fmaxf(cntf[g], 1.0f);
        float s4[4] = {a0, a1, a2, a3};
        float h2v[8];
#pragma unroll
        for (int j = 0; j < 8; j++) h2v[j] = h2[(size_t)g * 8 + j];
        int b = batch[g];
        int off = b - sbase;
        bool local = (off >= 0 && off < 16);
#pragma unroll
        for (int k = 0; k < 4; k++) {
            float z = 0.0f;
#pragma unroll
            for (int j = 0; j < 8; j++) z += h2v[j] * sW[j * 4 + k];
            float v = s4[k] * inv + sb[k] + z;
            if (local) atomicAdd(&lp[off][k], v);
            else atomicAdd(&pool[b * 4 + k], v);
        }
        if (local) atomicAdd(&lc[off], 1.0f);
        else atomicAdd(&gcnt[b], 1.0f);
    }
    __syncthreads();
    if (threadIdx.x < 16) {
        int b = sbase + threadIdx.x;
        float c = lc[threadIdx.x];
        if (c > 0.0f && b < N_GRAPHS) {
            atomicAdd(&gcnt[b], c);
            for (int k = 0; k < 4; k++) atomicAdd(&pool[b * 4 + k], lp[threadIdx.x][k]);
        }
    }
}

__global__ void final_k(const float* __restrict__ pool, const float* __restrict__ gcnt,
                        const float* __restrict__ Wc, const float* __restrict__ bc,
                        float* __restrict__ out) {
    int g = blockIdx.x * blockDim.x + threadIdx.x;
    if (g >= N_GRAPHS) return;
    float inv = 1.0f / fmaxf(gcnt[g], 1.0f);
    float acc = bc[0];
#pragma unroll
    for (int k = 0; k < 4; k++) {
        float ap = pool[g * 4 + k];
        acc += ap * inv * Wc[k] + ap * Wc[4 + k];
    }
    out[g] = acc;
}

extern "C" void kernel_launch(void* const* d_in, const int* in_sizes, int n_in,
                              void* d_out, int out_size, void* d_ws, size_t ws_size,
                              hipStream_t stream) {
    const float* x = (const float*)d_in[0];
    const int* ei = (const int*)d_in[1];
    const int* src = ei;
    const int* dst = ei + N_EDGES;
    const int* batch = (const int*)d_in[2];
    const float* W1l = (const float*)d_in[3];
    const float* b1 = (const float*)d_in[4];
    const float* W1r = (const float*)d_in[5];
    const float* W2l = (const float*)d_in[6];
    const float* b2 = (const float*)d_in[7];
    const float* W2r = (const float*)d_in[8];
    const float* W3l = (const float*)d_in[9];
    const float* b3 = (const float*)d_in[10];
    const float* W3r = (const float*)d_in[11];
    const float* Wc = (const float*)d_in[12];
    const float* bc = (const float*)d_in[13];
    float* out = (float*)d_out;

    const size_t N = N_NODES;
    unsigned* binned = (unsigned*)d_ws;                 // NSUB*CAPQ u32 ~= 20 MB
    int* qcnt = (int*)(binned + (size_t)NSUB * CAPQ);   // 2048 ints
    int* offs = qcnt + 2048;                            // NSUB*513 ints ~= 4 MB
    float* fbase = (float*)(offs + (size_t)NSUB * 513);
    float* cntf = fbase;                        // N
    float* z2 = cntf + N;                       // 8N (becomes h2 in place)
    unsigned* x16b = (unsigned*)(z2 + 8 * N);   // 8N u32
    unsigned* y2b = x16b + 8 * N;               // 4N u32
    unsigned* y3b = y2b + 4 * N;                // 2N u32
    float* pool = (float*)(y3b + 2 * N);        // 2048 (gcnt follows)
    float* gcnt = pool + N_GRAPHS * 4;          // 512

    const int TPB = 256;
    const int NB = (N_NODES + TPB - 1) / TPB;

    // 6 dispatches; zeroing folded into producers.
    pack_x<<<(N_NODES * 8 + TPB - 1) / TPB, TPB, 0, stream>>>(x, x16b, qcnt);
    partition_k<<<PART_BLOCKS, 1024, 0, stream>>>(src, dst, qcnt, binned);
    sortagg_k<<<NBINS, 1024, 0, stream>>>(x16b, binned, qcnt, offs, cntf,
                                          W1l, b1, W1r, W2l, W2r, y2b, z2);
    agg8f_k<<<NB, TPB, 0, stream>>>(y2b, binned, offs, cntf, b2, W3l, z2, y3b, pool);
    agg4pool_k<<<NB, TPB, 0, stream>>>(y3b, binned, offs, cntf, z2, W3r, b3, batch, pool, gcnt);
    final_k<<<2, TPB, 0, stream>>>(pool, gcnt, Wc, bc, out);
}

// Round 13
// 297.158 us; speedup vs baseline: 1.1946x; 1.1946x over previous
//
#include <hip/hip_runtime.h>

#define N_NODES 250000
#define N_EDGES 4000000
#define N_GRAPHS 512
#define NEG 0.01f
#define BINB 9
#define WIN 512
#define NBINS 489            // ceil(250000 / 512)
#define NSUB (NBINS * 4)     // dst-bin x src-quarter
#define CAPQ 2560            // per-sub-bin capacity: mean ~2045 + 11 sigma
#define PART_EPB 8192
#define PART_BLOCKS 489      // 489 * 8192 >= N_EDGES

__device__ __forceinline__ float lrelu(float v) { return v > 0.0f ? v : NEG * v; }
__device__ __forceinline__ unsigned f2b(float f) {
    unsigned u = __float_as_uint(f);
    unsigned r = ((u >> 16) & 1u) + 0x7FFFu;
    return (u + r) >> 16;
}
__device__ __forceinline__ unsigned pk(float a, float b) { return f2b(a) | (f2b(b) << 16); }
__device__ __forceinline__ float blo(unsigned p) { return __uint_as_float(p << 16); }
__device__ __forceinline__ float bhi(unsigned p) { return __uint_as_float(p & 0xFFFF0000u); }

// ---- Pack x into x16b (16 bf16 = 32 B rows); block 0 zeroes qcnt -------
__global__ void pack_x(const float* __restrict__ x, unsigned* __restrict__ x16b,
                       int* __restrict__ qcnt) {
    if (blockIdx.x == 0) {
        for (int i = threadIdx.x; i < NSUB; i += 256) qcnt[i] = 0;
    }
    int tid = blockIdx.x * blockDim.x + threadIdx.x;
    if (tid >= N_NODES * 8) return;
    int n = tid >> 3, d2 = tid & 7;
    int a = d2 * 2, b = a + 1;
    float va = (a < 13) ? x[n * 13 + a] : 0.0f;
    float vb = (b < 13) ? x[n * 13 + b] : 0.0f;
    x16b[tid] = pk(va, vb);
}

// ---- Edge binning with in-LDS sort by sub-bin (dense run writes) -------
__global__ __launch_bounds__(1024) void partition_k(const int* __restrict__ src,
                                                    const int* __restrict__ dst,
                                                    int* __restrict__ qcnt,
                                                    unsigned* __restrict__ binned) {
    __shared__ int hist[NSUB];            // later reused as scatter cursor
    __shared__ int loff[NSUB];
    __shared__ int base[NSUB];
    __shared__ unsigned ebuf[PART_EPB];
    __shared__ unsigned short subid[PART_EPB];
    __shared__ int wsum[16];
    int t = threadIdx.x;
    for (int i = t; i < NSUB; i += 1024) hist[i] = 0;
    __syncthreads();
    unsigned e0 = blockIdx.x * PART_EPB;
    int m = min((int)PART_EPB, (int)(N_EDGES - e0));
    for (int i = t; i < m; i += 1024) {
        unsigned e = e0 + i;
        int s = ((dst[e] >> BINB) << 2) | (src[e] >> 16);
        atomicAdd(&hist[s], 1);
    }
    __syncthreads();
    // exclusive scan over 1956 counters via 978 pairs + wave shuffles
    int p = 0, s0 = 0, incl = 0;
    if (t < NSUB / 2) { s0 = hist[2 * t]; p = s0 + hist[2 * t + 1]; }
    incl = p;
#pragma unroll
    for (int d = 1; d < 64; d <<= 1) {
        int u = __shfl_up(incl, d, 64);
        if ((t & 63) >= d) incl += u;
    }
    if ((t & 63) == 63) wsum[t >> 6] = incl;
    __syncthreads();
    if (t == 0) {
        int r = 0;
#pragma unroll
        for (int i = 0; i < 16; i++) { int s = wsum[i]; wsum[i] = r; r += s; }
    }
    __syncthreads();
    if (t < NSUB / 2) {
        int ex = incl + wsum[t >> 6] - p;
        loff[2 * t] = ex;
        loff[2 * t + 1] = ex + s0;
    }
    __syncthreads();
    // reserve global chunks (uses hist), then hist becomes cursor = loff
    for (int i = t; i < NSUB; i += 1024) {
        int h = hist[i];
        base[i] = (h > 0) ? atomicAdd(&qcnt[i], h) : 0;
    }
    __syncthreads();
    for (int i = t; i < NSUB; i += 1024) hist[i] = loff[i];
    __syncthreads();
    // pass 2: re-read edges, scatter into LDS sorted-by-sub order
    for (int i = t; i < m; i += 1024) {
        unsigned e = e0 + i;
        int d = dst[e], sv = src[e];
        int s = ((d >> BINB) << 2) | (sv >> 16);
        int pos = atomicAdd(&hist[s], 1);
        ebuf[pos] = ((unsigned)(d & (WIN - 1)) << 18) | (unsigned)sv;
        subid[pos] = (unsigned short)s;
    }
    __syncthreads();
    // write-out: consecutive lanes hit consecutive addresses of each run
    for (int j = t; j < m; j += 1024) {
        int s = subid[j];
        binned[(size_t)s * CAPQ + base[s] + (j - loff[s])] = ebuf[j];
    }
}

// ---- Counting sort each sub-bin by dst + fused layer-1 aggregation -----
__global__ __launch_bounds__(1024) void sortagg_k(const unsigned* __restrict__ x16b,
                                                  unsigned* __restrict__ binned,
                                                  const int* __restrict__ qcnt,
                                                  int* __restrict__ offs,
                                                  float* __restrict__ cntf,
                                                  float* __restrict__ agg) {
    __shared__ unsigned stg[CAPQ];
    __shared__ unsigned srt[CAPQ];
    __shared__ int hist[WIN];
    __shared__ int cur[WIN];
    __shared__ int wsum[8];
    int t = threadIdx.x;
    int bin = blockIdx.x;
    int f = t & (WIN - 1), l = t >> 9;
    int lane = t & 63, wv = t >> 6;
    float a0 = 0, a1 = 0, a2 = 0, a3 = 0, a4 = 0, a5 = 0, a6 = 0, a7 = 0;
    int deg = 0;
    for (int q = 0; q < 4; q++) {
        int sub = (bin << 2) | q;
        int cnt = qcnt[sub];
        unsigned* bp = binned + (size_t)sub * CAPQ;
        if (t < WIN) hist[t] = 0;
        __syncthreads();
        for (int i = t; i < cnt; i += 1024) {
            unsigned w = bp[i];
            stg[i] = w;
            atomicAdd(&hist[w >> 18], 1);
        }
        __syncthreads();
        // wave-shuffle inclusive scan over 512 counters (waves 0..7)
        int v = (t < WIN) ? hist[t] : 0;
#pragma unroll
        for (int d = 1; d < 64; d <<= 1) {
            int u = __shfl_up(v, d, 64);
            if (lane >= d) v += u;
        }
        if (t < WIN && lane == 63) wsum[wv] = v;
        __syncthreads();
        if (t == 0) {
            int r = 0;
#pragma unroll
            for (int i = 0; i < 8; i++) { int s = wsum[i]; wsum[i] = r; r += s; }
        }
        __syncthreads();
        if (t < WIN) {
            int incl = v + wsum[wv];
            int ex = incl - hist[t];
            cur[t] = ex;
            offs[(size_t)sub * 513 + t] = ex;
            deg += hist[t];
        }
        if (t == 0) offs[(size_t)sub * 513 + WIN] = cnt;
        __syncthreads();
        for (int i = t; i < cnt; i += 1024) {
            unsigned w = stg[i];
            int pos = atomicAdd(&cur[w >> 18], 1);
            srt[pos] = w;
        }
        __syncthreads();
        for (int i = t; i < cnt; i += 1024) bp[i] = srt[i];
        // fused layer-1 gather from LDS-resident sorted run
        int e_ = cur[f];
        int s_ = e_ - hist[f];
        int k = s_;
        for (; k + 4 <= e_; k += 4) {
            unsigned w0 = srt[k], w1 = srt[k + 1], w2 = srt[k + 2], w3 = srt[k + 3];
            uint4 v0 = *(const uint4*)&x16b[(size_t)(w0 & 0x3FFFFu) * 8u + (unsigned)(l * 4)];
            uint4 v1 = *(const uint4*)&x16b[(size_t)(w1 & 0x3FFFFu) * 8u + (unsigned)(l * 4)];
            uint4 v2 = *(const uint4*)&x16b[(size_t)(w2 & 0x3FFFFu) * 8u + (unsigned)(l * 4)];
            uint4 v3 = *(const uint4*)&x16b[(size_t)(w3 & 0x3FFFFu) * 8u + (unsigned)(l * 4)];
            a0 += blo(v0.x) + blo(v1.x) + blo(v2.x) + blo(v3.x);
            a1 += bhi(v0.x) + bhi(v1.x) + bhi(v2.x) + bhi(v3.x);
            a2 += blo(v0.y) + blo(v1.y) + blo(v2.y) + blo(v3.y);
            a3 += bhi(v0.y) + bhi(v1.y) + bhi(v2.y) + bhi(v3.y);
            a4 += blo(v0.z) + blo(v1.z) + blo(v2.z) + blo(v3.z);
            a5 += bhi(v0.z) + bhi(v1.z) + bhi(v2.z) + bhi(v3.z);
            a6 += blo(v0.w) + blo(v1.w) + blo(v2.w) + blo(v3.w);
            a7 += bhi(v0.w) + bhi(v1.w) + bhi(v2.w) + bhi(v3.w);
        }
        for (; k < e_; k++) {
            unsigned w = srt[k];
            uint4 v4 = *(const uint4*)&x16b[(size_t)(w & 0x3FFFFu) * 8u + (unsigned)(l * 4)];
            a0 += blo(v4.x); a1 += bhi(v4.x); a2 += blo(v4.y); a3 += bhi(v4.y);
            a4 += blo(v4.z); a5 += bhi(v4.z); a6 += blo(v4.w); a7 += bhi(v4.w);
        }
        __syncthreads();
    }
    int g = (bin << BINB) + f;
    if (g < N_NODES) {
        size_t b = (size_t)g * 13;
        if (l == 0) {
            agg[b + 0] = a0; agg[b + 1] = a1; agg[b + 2] = a2; agg[b + 3] = a3;
            agg[b + 4] = a4; agg[b + 5] = a5; agg[b + 6] = a6; agg[b + 7] = a7;
            cntf[g] = (float)deg;
        } else {
            agg[b + 8] = a0; agg[b + 9] = a1; agg[b + 10] = a2;
            agg[b + 11] = a3; agg[b + 12] = a4;
        }
    }
}

// ---- Node linear 1: h1, y2b, z2 ----------------------------------------
__global__ void fused1(const float* __restrict__ agg, const float* __restrict__ x,
                       const float* __restrict__ cntf,
                       const float* __restrict__ W1l, const float* __restrict__ b1,
                       const float* __restrict__ W1r, const float* __restrict__ W2l,
                       const float* __restrict__ W2r,
                       unsigned* __restrict__ y2b, float* __restrict__ z2) {
    __shared__ float sWl[208], sWr[208], sb[16], sA[128], sB[128];
    for (int i = threadIdx.x; i < 208; i += blockDim.x) { sWl[i] = W1l[i]; sWr[i] = W1r[i]; }
    for (int i = threadIdx.x; i < 128; i += blockDim.x) { sA[i] = W2l[i]; sB[i] = W2r[i]; }
    if (threadIdx.x < 16) sb[threadIdx.x] = b1[threadIdx.x];
    __syncthreads();
    int n = blockIdx.x * blockDim.x + threadIdx.x;
    if (n >= N_NODES) return;
    float inv = 1.0f / fmaxf(cntf[n], 1.0f);
    float a[13], xv[13];
#pragma unroll
    for (int i = 0; i < 13; i++) { a[i] = agg[n * 13 + i] * inv; xv[i] = x[n * 13 + i]; }
    float h[16];
#pragma unroll
    for (int o = 0; o < 16; o++) {
        float acc = sb[o];
#pragma unroll
        for (int i = 0; i < 13; i++) acc += a[i] * sWl[i * 16 + o] + xv[i] * sWr[i * 16 + o];
        h[o] = lrelu(acc);
    }
    float ya[8];
#pragma unroll
    for (int o2 = 0; o2 < 8; o2++) {
        float y = 0.0f, za = 0.0f;
#pragma unroll
        for (int o = 0; o < 16; o++) { y += h[o] * sA[o * 8 + o2]; za += h[o] * sB[o * 8 + o2]; }
        ya[o2] = y;
        z2[n * 8 + o2] = za;
    }
    uint4 out;
    out.x = pk(ya[0], ya[1]); out.y = pk(ya[2], ya[3]);
    out.z = pk(ya[4], ya[5]); out.w = pk(ya[6], ya[7]);
    *(uint4*)&y2b[(size_t)n * 4u] = out;
}

// ---- Layer-2 gather + fused epilogue: h2 (in z2), y3b ------------------
__global__ __launch_bounds__(256) void agg8f_k(const unsigned* __restrict__ y2b,
                                               const unsigned* __restrict__ binned,
                                               const int* __restrict__ offs,
                                               const float* __restrict__ cntf,
                                               const float* __restrict__ b2,
                                               const float* __restrict__ W3l,
                                               float* __restrict__ z2h2,
                                               unsigned* __restrict__ y3b,
                                               float* __restrict__ pool) {
    __shared__ float sb[8], sW3[32];
    if (blockIdx.x == 0) {
        for (int i = threadIdx.x; i < N_GRAPHS * 5; i += 256) pool[i] = 0.0f;
    }
    if (threadIdx.x < 8) sb[threadIdx.x] = b2[threadIdx.x];
    if (threadIdx.x < 32) sW3[threadIdx.x] = W3l[threadIdx.x];
    __syncthreads();
    int g = blockIdx.x * 256 + threadIdx.x;
    if (g >= N_NODES) return;
    int bin = g >> BINB, f = g & (WIN - 1);
    float a0 = 0, a1 = 0, a2 = 0, a3 = 0, a4 = 0, a5 = 0, a6 = 0, a7 = 0;
#pragma unroll
    for (int q = 0; q < 4; q++) {
        int sub = (bin << 2) | q;
        const int* o = offs + (size_t)sub * 513;
        int s = o[f], e = o[f + 1];
        const unsigned* bp = binned + (size_t)sub * CAPQ;
        int k = s;
        for (; k + 4 <= e; k += 4) {
            unsigned w0 = bp[k], w1 = bp[k + 1], w2 = bp[k + 2], w3 = bp[k + 3];
            uint4 v0 = *(const uint4*)&y2b[(size_t)(w0 & 0x3FFFFu) * 4u];
            uint4 v1 = *(const uint4*)&y2b[(size_t)(w1 & 0x3FFFFu) * 4u];
            uint4 v2 = *(const uint4*)&y2b[(size_t)(w2 & 0x3FFFFu) * 4u];
            uint4 v3 = *(const uint4*)&y2b[(size_t)(w3 & 0x3FFFFu) * 4u];
            a0 += blo(v0.x) + blo(v1.x) + blo(v2.x) + blo(v3.x);
            a1 += bhi(v0.x) + bhi(v1.x) + bhi(v2.x) + bhi(v3.x);
            a2 += blo(v0.y) + blo(v1.y) + blo(v2.y) + blo(v3.y);
            a3 += bhi(v0.y) + bhi(v1.y) + bhi(v2.y) + bhi(v3.y);
            a4 += blo(v0.z) + blo(v1.z) + blo(v2.z) + blo(v3.z);
            a5 += bhi(v0.z) + bhi(v1.z) + bhi(v2.z) + bhi(v3.z);
            a6 += blo(v0.w) + blo(v1.w) + blo(v2.w) + blo(v3.w);
            a7 += bhi(v0.w) + bhi(v1.w) + bhi(v2.w) + bhi(v3.w);
        }
        for (; k < e; k++) {
            uint4 v = *(const uint4*)&y2b[(size_t)(bp[k] & 0x3FFFFu) * 4u];
            a0 += blo(v.x); a1 += bhi(v.x); a2 += blo(v.y); a3 += bhi(v.y);
            a4 += blo(v.z); a5 += bhi(v.z); a6 += blo(v.w); a7 += bhi(v.w);
        }
    }
    float inv = 1.0f / fmaxf(cntf[g], 1.0f);
    float h2v[8];
    float s8[8] = {a0, a1, a2, a3, a4, a5, a6, a7};
#pragma unroll
    for (int j = 0; j < 8; j++) {
        float v = s8[j] * inv + sb[j] + z2h2[(size_t)g * 8 + j];
        h2v[j] = lrelu(v);
        z2h2[(size_t)g * 8 + j] = h2v[j];
    }
    float y[4];
#pragma unroll
    for (int k = 0; k < 4; k++) {
        float acc = 0.0f;
#pragma unroll
        for (int j = 0; j < 8; j++) acc += h2v[j] * sW3[j * 4 + k];
        y[k] = acc;
    }
    uint2 out;
    out.x = pk(y[0], y[1]); out.y = pk(y[2], y[3]);
    *(uint2*)&y3b[(size_t)g * 2u] = out;
}

// ---- Layer-3 gather + fused epilogue + pooling -------------------------
__global__ __launch_bounds__(256) void agg4pool_k(const unsigned* __restrict__ y3b,
                                                  const unsigned* __restrict__ binned,
                                                  const int* __restrict__ offs,
                                                  const float* __restrict__ cntf,
                                                  const float* __restrict__ h2,
                                                  const float* __restrict__ W3r,
                                                  const float* __restrict__ b3,
                                                  const int* __restrict__ batch,
                                                  float* __restrict__ pool,
                                                  float* __restrict__ gcnt) {
    __shared__ float sW[32], sb[4];
    __shared__ float lp[16][4];
    __shared__ float lc[16];
    __shared__ int sbase;
    if (threadIdx.x < 32) sW[threadIdx.x] = W3r[threadIdx.x];
    if (threadIdx.x < 4) sb[threadIdx.x] = b3[threadIdx.x];
    if (threadIdx.x < 16) {
        lc[threadIdx.x] = 0.0f;
        for (int k = 0; k < 4; k++) lp[threadIdx.x][k] = 0.0f;
    }
    int n0 = blockIdx.x * 256;
    if (threadIdx.x == 0) sbase = batch[n0 < N_NODES ? n0 : N_NODES - 1];
    __syncthreads();
    int g = n0 + threadIdx.x;
    if (g < N_NODES) {
        int bin = g >> BINB, f = g & (WIN - 1);
        float a0 = 0, a1 = 0, a2 = 0, a3 = 0;
#pragma unroll
        for (int q = 0; q < 4; q++) {
            int sub = (bin << 2) | q;
            const int* o = offs + (size_t)sub * 513;
            int s = o[f], e = o[f + 1];
            const unsigned* bp = binned + (size_t)sub * CAPQ;
            int k = s;
            for (; k + 4 <= e; k += 4) {
                unsigned w0 = bp[k], w1 = bp[k + 1], w2 = bp[k + 2], w3 = bp[k + 3];
                uint2 v0 = *(const uint2*)&y3b[(size_t)(w0 & 0x3FFFFu) * 2u];
                uint2 v1 = *(const uint2*)&y3b[(size_t)(w1 & 0x3FFFFu) * 2u];
                uint2 v2 = *(const uint2*)&y3b[(size_t)(w2 & 0x3FFFFu) * 2u];
                uint2 v3 = *(const uint2*)&y3b[(size_t)(w3 & 0x3FFFFu) * 2u];
                a0 += blo(v0.x) + blo(v1.x) + blo(v2.x) + blo(v3.x);
                a1 += bhi(v0.x) + bhi(v1.x) + bhi(v2.x) + bhi(v3.x);
                a2 += blo(v0.y) + blo(v1.y) + blo(v2.y) + blo(v3.y);
                a3 += bhi(v0.y) + bhi(v1.y) + bhi(v2.y) + bhi(v3.y);
            }
            for (; k < e; k++) {
                uint2 v = *(const uint2*)&y3b[(size_t)(bp[k] & 0x3FFFFu) * 2u];
                a0 += blo(v.x); a1 += bhi(v.x); a2 += blo(v.y); a3 += bhi(v.y);
            }
        }
        float inv = 1.0f / fmaxf(cntf[g], 1.0f);
        float s4[4] = {a0, a1, a2, a3};
        float h2v[8];
#pragma unroll
        for (int j = 0; j < 8; j++) h2v[j] = h2[(size_t)g * 8 + j];
        int b = batch[g];
        int off = b - sbase;
        bool local = (off >= 0 && off < 16);
#pragma unroll
        for (int k = 0; k < 4; k++) {
            float z = 0.0f;
#pragma unroll
            for (int j = 0; j < 8; j++) z += h2v[j] * sW[j * 4 + k];
            float v = s4[k] * inv + sb[k] + z;
            if (local) atomicAdd(&lp[off][k], v);
            else atomicAdd(&pool[b * 4 + k], v);
        }
        if (local) atomicAdd(&lc[off], 1.0f);
        else atomicAdd(&gcnt[b], 1.0f);
    }
    __syncthreads();
    if (threadIdx.x < 16) {
        int b = sbase + threadIdx.x;
        float c = lc[threadIdx.x];
        if (c > 0.0f && b < N_GRAPHS) {
            atomicAdd(&gcnt[b], c);
            for (int k = 0; k < 4; k++) atomicAdd(&pool[b * 4 + k], lp[threadIdx.x][k]);
        }
    }
}

__global__ void final_k(const float* __restrict__ pool, const float* __restrict__ gcnt,
                        const float* __restrict__ Wc, const float* __restrict__ bc,
                        float* __restrict__ out) {
    int g = blockIdx.x * blockDim.x + threadIdx.x;
    if (g >= N_GRAPHS) return;
    float inv = 1.0f / fmaxf(gcnt[g], 1.0f);
    float acc = bc[0];
#pragma unroll
    for (int k = 0; k < 4; k++) {
        float ap = pool[g * 4 + k];
        acc += ap * inv * Wc[k] + ap * Wc[4 + k];
    }
    out[g] = acc;
}

extern "C" void kernel_launch(void* const* d_in, const int* in_sizes, int n_in,
                              void* d_out, int out_size, void* d_ws, size_t ws_size,
                              hipStream_t stream) {
    const float* x = (const float*)d_in[0];
    const int* ei = (const int*)d_in[1];
    const int* src = ei;
    const int* dst = ei + N_EDGES;
    const int* batch = (const int*)d_in[2];
    const float* W1l = (const float*)d_in[3];
    const float* b1 = (const float*)d_in[4];
    const float* W1r = (const float*)d_in[5];
    const float* W2l = (const float*)d_in[6];
    const float* b2 = (const float*)d_in[7];
    const float* W2r = (const float*)d_in[8];
    const float* W3l = (const float*)d_in[9];
    const float* b3 = (const float*)d_in[10];
    const float* W3r = (const float*)d_in[11];
    const float* Wc = (const float*)d_in[12];
    const float* bc = (const float*)d_in[13];
    float* out = (float*)d_out;

    const size_t N = N_NODES;
    unsigned* binned = (unsigned*)d_ws;                 // NSUB*CAPQ u32 ~= 20 MB
    int* qcnt = (int*)(binned + (size_t)NSUB * CAPQ);   // 2048 ints
    int* offs = qcnt + 2048;                            // NSUB*513 ints ~= 4 MB
    float* fbase = (float*)(offs + (size_t)NSUB * 513);
    float* agg = fbase;                         // 13N floats
    float* cntf = fbase + 13 * N;               // N
    float* z2 = cntf + N;                       // 8N (becomes h2 in place)
    unsigned* x16b = (unsigned*)(z2 + 8 * N);   // 8N u32
    unsigned* y2b = x16b + 8 * N;               // 4N u32
    unsigned* y3b = y2b + 4 * N;                // 2N u32
    float* pool = (float*)(y3b + 2 * N);        // 2048 (gcnt follows)
    float* gcnt = pool + N_GRAPHS * 4;          // 512

    const int TPB = 256;
    const int NB = (N_NODES + TPB - 1) / TPB;

    // 7 dispatches; zeroing folded into producers.
    pack_x<<<(N_NODES * 8 + TPB - 1) / TPB, TPB, 0, stream>>>(x, x16b, qcnt);
    partition_k<<<PART_BLOCKS, 1024, 0, stream>>>(src, dst, qcnt, binned);
    sortagg_k<<<NBINS, 1024, 0, stream>>>(x16b, binned, qcnt, offs, cntf, agg);
    fused1<<<NB, TPB, 0, stream>>>(agg, x, cntf, W1l, b1, W1r, W2l, W2r, y2b, z2);
    agg8f_k<<<NB, TPB, 0, stream>>>(y2b, binned, offs, cntf, b2, W3l, z2, y3b, pool);
    agg4pool_k<<<NB, TPB, 0, stream>>>(y3b, binned, offs, cntf, z2, W3r, b3, batch, pool, gcnt);
    final_k<<<2, TPB, 0, stream>>>(pool, gcnt, Wc, bc, out);
}

// Round 14
// 276.310 us; speedup vs baseline: 1.2847x; 1.0755x over previous
//
#include <hip/hip_runtime.h>

#define N_NODES 250000
#define N_EDGES 4000000
#define N_GRAPHS 512
#define NEG 0.01f
#define BINB 9
#define WIN 512
#define NBINS 489            // ceil(250000 / 512)
#define NSUB (NBINS * 4)     // dst-bin x src-quarter
#define CAPQ 2560            // per-sub-bin capacity: mean ~2045 + 11 sigma
#define PART_EPB 8192
#define PART_BLOCKS 489      // 489 * 8192 >= N_EDGES

__device__ __forceinline__ float lrelu(float v) { return v > 0.0f ? v : NEG * v; }
__device__ __forceinline__ unsigned f2b(float f) {
    unsigned u = __float_as_uint(f);
    unsigned r = ((u >> 16) & 1u) + 0x7FFFu;
    return (u + r) >> 16;
}
__device__ __forceinline__ unsigned pk(float a, float b) { return f2b(a) | (f2b(b) << 16); }
__device__ __forceinline__ float blo(unsigned p) { return __uint_as_float(p << 16); }
__device__ __forceinline__ float bhi(unsigned p) { return __uint_as_float(p & 0xFFFF0000u); }

// ---- Pack x into x16b (16 bf16 = 32 B rows); block 0 zeroes qcnt -------
__global__ __launch_bounds__(256) void pack_x(const float* __restrict__ x,
                                              unsigned* __restrict__ x16b,
                                              int* __restrict__ qcnt) {
    if (blockIdx.x == 0) {
        for (int i = threadIdx.x; i < NSUB; i += 256) qcnt[i] = 0;
    }
    int tid = blockIdx.x * blockDim.x + threadIdx.x;
    if (tid >= N_NODES * 8) return;
    int n = tid >> 3, d2 = tid & 7;
    int a = d2 * 2, b = a + 1;
    float va = (a < 13) ? x[n * 13 + a] : 0.0f;
    float vb = (b < 13) ? x[n * 13 + b] : 0.0f;
    x16b[tid] = pk(va, vb);
}

// ---- Edge binning with in-LDS sort by sub-bin (dense run writes) -------
__global__ __launch_bounds__(1024) void partition_k(const int* __restrict__ src,
                                                    const int* __restrict__ dst,
                                                    int* __restrict__ qcnt,
                                                    unsigned* __restrict__ binned) {
    __shared__ int hist[NSUB];            // later reused as scatter cursor
    __shared__ int loff[NSUB];
    __shared__ int base[NSUB];
    __shared__ unsigned ebuf[PART_EPB];
    __shared__ unsigned short subid[PART_EPB];
    __shared__ int wsum[16];
    int t = threadIdx.x;
    for (int i = t; i < NSUB; i += 1024) hist[i] = 0;
    __syncthreads();
    unsigned e0 = blockIdx.x * PART_EPB;
    int m = min((int)PART_EPB, (int)(N_EDGES - e0));
    for (int i = t; i < m; i += 1024) {
        unsigned e = e0 + i;
        int s = ((dst[e] >> BINB) << 2) | (src[e] >> 16);
        atomicAdd(&hist[s], 1);
    }
    __syncthreads();
    // exclusive scan over 1956 counters via 978 pairs + wave shuffles
    int p = 0, s0 = 0, incl = 0;
    if (t < NSUB / 2) { s0 = hist[2 * t]; p = s0 + hist[2 * t + 1]; }
    incl = p;
#pragma unroll
    for (int d = 1; d < 64; d <<= 1) {
        int u = __shfl_up(incl, d, 64);
        if ((t & 63) >= d) incl += u;
    }
    if ((t & 63) == 63) wsum[t >> 6] = incl;
    __syncthreads();
    if (t == 0) {
        int r = 0;
#pragma unroll
        for (int i = 0; i < 16; i++) { int s = wsum[i]; wsum[i] = r; r += s; }
    }
    __syncthreads();
    if (t < NSUB / 2) {
        int ex = incl + wsum[t >> 6] - p;
        loff[2 * t] = ex;
        loff[2 * t + 1] = ex + s0;
    }
    __syncthreads();
    // reserve global chunks (uses hist), then hist becomes cursor = loff
    for (int i = t; i < NSUB; i += 1024) {
        int h = hist[i];
        base[i] = (h > 0) ? atomicAdd(&qcnt[i], h) : 0;
    }
    __syncthreads();
    for (int i = t; i < NSUB; i += 1024) hist[i] = loff[i];
    __syncthreads();
    // pass 2: re-read edges, scatter into LDS sorted-by-sub order
    for (int i = t; i < m; i += 1024) {
        unsigned e = e0 + i;
        int d = dst[e], sv = src[e];
        int s = ((d >> BINB) << 2) | (sv >> 16);
        int pos = atomicAdd(&hist[s], 1);
        ebuf[pos] = ((unsigned)(d & (WIN - 1)) << 18) | (unsigned)sv;
        subid[pos] = (unsigned short)s;
    }
    __syncthreads();
    // write-out: consecutive lanes hit consecutive addresses of each run
    for (int j = t; j < m; j += 1024) {
        int s = subid[j];
        binned[(size_t)s * CAPQ + base[s] + (j - loff[s])] = ebuf[j];
    }
}

// ---- Counting sort each sub-bin by dst + fused layer-1 aggregation -----
__global__ __launch_bounds__(1024) void sortagg_k(const unsigned* __restrict__ x16b,
                                                  unsigned* __restrict__ binned,
                                                  const int* __restrict__ qcnt,
                                                  int* __restrict__ offs,
                                                  float* __restrict__ cntf,
                                                  float* __restrict__ agg) {
    __shared__ unsigned stg[CAPQ];
    __shared__ unsigned srt[CAPQ];
    __shared__ int hist[WIN];
    __shared__ int cur[WIN];
    __shared__ int wsum[8];
    int t = threadIdx.x;
    int bin = blockIdx.x;
    int f = t & (WIN - 1), l = t >> 9;
    int lane = t & 63, wv = t >> 6;
    float a0 = 0, a1 = 0, a2 = 0, a3 = 0, a4 = 0, a5 = 0, a6 = 0, a7 = 0;
    int deg = 0;
    for (int q = 0; q < 4; q++) {
        int sub = (bin << 2) | q;
        int cnt = qcnt[sub];
        unsigned* bp = binned + (size_t)sub * CAPQ;
        if (t < WIN) hist[t] = 0;
        __syncthreads();
        for (int i = t; i < cnt; i += 1024) {
            unsigned w = bp[i];
            stg[i] = w;
            atomicAdd(&hist[w >> 18], 1);
        }
        __syncthreads();
        // wave-shuffle inclusive scan over 512 counters (waves 0..7)
        int v = (t < WIN) ? hist[t] : 0;
#pragma unroll
        for (int d = 1; d < 64; d <<= 1) {
            int u = __shfl_up(v, d, 64);
            if (lane >= d) v += u;
        }
        if (t < WIN && lane == 63) wsum[wv] = v;
        __syncthreads();
        if (t == 0) {
            int r = 0;
#pragma unroll
            for (int i = 0; i < 8; i++) { int s = wsum[i]; wsum[i] = r; r += s; }
        }
        __syncthreads();
        if (t < WIN) {
            int incl = v + wsum[wv];
            int ex = incl - hist[t];
            cur[t] = ex;
            offs[(size_t)sub * 513 + t] = ex;
            deg += hist[t];
        }
        if (t == 0) offs[(size_t)sub * 513 + WIN] = cnt;
        __syncthreads();
        for (int i = t; i < cnt; i += 1024) {
            unsigned w = stg[i];
            int pos = atomicAdd(&cur[w >> 18], 1);
            srt[pos] = w;
        }
        __syncthreads();
        for (int i = t; i < cnt; i += 1024) bp[i] = srt[i];
        // fused layer-1 gather from LDS-resident sorted run
        int e_ = cur[f];
        int s_ = e_ - hist[f];
        int k = s_;
        for (; k + 4 <= e_; k += 4) {
            unsigned w0 = srt[k], w1 = srt[k + 1], w2 = srt[k + 2], w3 = srt[k + 3];
            uint4 v0 = *(const uint4*)&x16b[(size_t)(w0 & 0x3FFFFu) * 8u + (unsigned)(l * 4)];
            uint4 v1 = *(const uint4*)&x16b[(size_t)(w1 & 0x3FFFFu) * 8u + (unsigned)(l * 4)];
            uint4 v2 = *(const uint4*)&x16b[(size_t)(w2 & 0x3FFFFu) * 8u + (unsigned)(l * 4)];
            uint4 v3 = *(const uint4*)&x16b[(size_t)(w3 & 0x3FFFFu) * 8u + (unsigned)(l * 4)];
            a0 += blo(v0.x) + blo(v1.x) + blo(v2.x) + blo(v3.x);
            a1 += bhi(v0.x) + bhi(v1.x) + bhi(v2.x) + bhi(v3.x);
            a2 += blo(v0.y) + blo(v1.y) + blo(v2.y) + blo(v3.y);
            a3 += bhi(v0.y) + bhi(v1.y) + bhi(v2.y) + bhi(v3.y);
            a4 += blo(v0.z) + blo(v1.z) + blo(v2.z) + blo(v3.z);
            a5 += bhi(v0.z) + bhi(v1.z) + bhi(v2.z) + bhi(v3.z);
            a6 += blo(v0.w) + blo(v1.w) + blo(v2.w) + blo(v3.w);
            a7 += bhi(v0.w) + bhi(v1.w) + bhi(v2.w) + bhi(v3.w);
        }
        for (; k < e_; k++) {
            unsigned w = srt[k];
            uint4 v4 = *(const uint4*)&x16b[(size_t)(w & 0x3FFFFu) * 8u + (unsigned)(l * 4)];
            a0 += blo(v4.x); a1 += bhi(v4.x); a2 += blo(v4.y); a3 += bhi(v4.y);
            a4 += blo(v4.z); a5 += bhi(v4.z); a6 += blo(v4.w); a7 += bhi(v4.w);
        }
        __syncthreads();
    }
    int g = (bin << BINB) + f;
    if (g < N_NODES) {
        size_t b = (size_t)g * 13;
        if (l == 0) {
            agg[b + 0] = a0; agg[b + 1] = a1; agg[b + 2] = a2; agg[b + 3] = a3;
            agg[b + 4] = a4; agg[b + 5] = a5; agg[b + 6] = a6; agg[b + 7] = a7;
            cntf[g] = (float)deg;
        } else {
            agg[b + 8] = a0; agg[b + 9] = a1; agg[b + 10] = a2;
            agg[b + 11] = a3; agg[b + 12] = a4;
        }
    }
}

// ---- Node linear 1: h1, y2b, z2 ----------------------------------------
// __launch_bounds__(256) is load-bearing: without it hipcc compiles for
// 1024-thread worst case -> 64 VGPR cap -> ~55 live floats spill to
// scratch (~165 MB of spill traffic, 54 us). With it: no spill.
__global__ __launch_bounds__(256) void fused1(const float* __restrict__ agg,
                                              const float* __restrict__ x,
                                              const float* __restrict__ cntf,
                                              const float* __restrict__ W1l,
                                              const float* __restrict__ b1,
                                              const float* __restrict__ W1r,
                                              const float* __restrict__ W2l,
                                              const float* __restrict__ W2r,
                                              unsigned* __restrict__ y2b,
                                              float* __restrict__ z2) {
    __shared__ float sWl[208], sWr[208], sb[16], sA[128], sB[128];
    for (int i = threadIdx.x; i < 208; i += blockDim.x) { sWl[i] = W1l[i]; sWr[i] = W1r[i]; }
    for (int i = threadIdx.x; i < 128; i += blockDim.x) { sA[i] = W2l[i]; sB[i] = W2r[i]; }
    if (threadIdx.x < 16) sb[threadIdx.x] = b1[threadIdx.x];
    __syncthreads();
    int n = blockIdx.x * blockDim.x + threadIdx.x;
    if (n >= N_NODES) return;
    float inv = 1.0f / fmaxf(cntf[n], 1.0f);
    float a[13], xv[13];
#pragma unroll
    for (int i = 0; i < 13; i++) { a[i] = agg[n * 13 + i] * inv; xv[i] = x[n * 13 + i]; }
    float h[16];
#pragma unroll
    for (int o = 0; o < 16; o++) {
        float acc = sb[o];
#pragma unroll
        for (int i = 0; i < 13; i++) acc += a[i] * sWl[i * 16 + o] + xv[i] * sWr[i * 16 + o];
        h[o] = lrelu(acc);
    }
    float ya[8];
#pragma unroll
    for (int o2 = 0; o2 < 8; o2++) {
        float y = 0.0f, za = 0.0f;
#pragma unroll
        for (int o = 0; o < 16; o++) { y += h[o] * sA[o * 8 + o2]; za += h[o] * sB[o * 8 + o2]; }
        ya[o2] = y;
        z2[n * 8 + o2] = za;
    }
    uint4 out;
    out.x = pk(ya[0], ya[1]); out.y = pk(ya[2], ya[3]);
    out.z = pk(ya[4], ya[5]); out.w = pk(ya[6], ya[7]);
    *(uint4*)&y2b[(size_t)n * 4u] = out;
}

// ---- Layer-2 gather + fused epilogue: h2 (in z2), y3b ------------------
__global__ __launch_bounds__(256) void agg8f_k(const unsigned* __restrict__ y2b,
                                               const unsigned* __restrict__ binned,
                                               const int* __restrict__ offs,
                                               const float* __restrict__ cntf,
                                               const float* __restrict__ b2,
                                               const float* __restrict__ W3l,
                                               float* __restrict__ z2h2,
                                               unsigned* __restrict__ y3b,
                                               float* __restrict__ pool) {
    __shared__ float sb[8], sW3[32];
    if (blockIdx.x == 0) {
        for (int i = threadIdx.x; i < N_GRAPHS * 5; i += 256) pool[i] = 0.0f;
    }
    if (threadIdx.x < 8) sb[threadIdx.x] = b2[threadIdx.x];
    if (threadIdx.x < 32) sW3[threadIdx.x] = W3l[threadIdx.x];
    __syncthreads();
    int g = blockIdx.x * 256 + threadIdx.x;
    if (g >= N_NODES) return;
    int bin = g >> BINB, f = g & (WIN - 1);
    float a0 = 0, a1 = 0, a2 = 0, a3 = 0, a4 = 0, a5 = 0, a6 = 0, a7 = 0;
#pragma unroll
    for (int q = 0; q < 4; q++) {
        int sub = (bin << 2) | q;
        const int* o = offs + (size_t)sub * 513;
        int s = o[f], e = o[f + 1];
        const unsigned* bp = binned + (size_t)sub * CAPQ;
        int k = s;
        for (; k + 4 <= e; k += 4) {
            unsigned w0 = bp[k], w1 = bp[k + 1], w2 = bp[k + 2], w3 = bp[k + 3];
            uint4 v0 = *(const uint4*)&y2b[(size_t)(w0 & 0x3FFFFu) * 4u];
            uint4 v1 = *(const uint4*)&y2b[(size_t)(w1 & 0x3FFFFu) * 4u];
            uint4 v2 = *(const uint4*)&y2b[(size_t)(w2 & 0x3FFFFu) * 4u];
            uint4 v3 = *(const uint4*)&y2b[(size_t)(w3 & 0x3FFFFu) * 4u];
            a0 += blo(v0.x) + blo(v1.x) + blo(v2.x) + blo(v3.x);
            a1 += bhi(v0.x) + bhi(v1.x) + bhi(v2.x) + bhi(v3.x);
            a2 += blo(v0.y) + blo(v1.y) + blo(v2.y) + blo(v3.y);
            a3 += bhi(v0.y) + bhi(v1.y) + bhi(v2.y) + bhi(v3.y);
            a4 += blo(v0.z) + blo(v1.z) + blo(v2.z) + blo(v3.z);
            a5 += bhi(v0.z) + bhi(v1.z) + bhi(v2.z) + bhi(v3.z);
            a6 += blo(v0.w) + blo(v1.w) + blo(v2.w) + blo(v3.w);
            a7 += bhi(v0.w) + bhi(v1.w) + bhi(v2.w) + bhi(v3.w);
        }
        for (; k < e; k++) {
            uint4 v = *(const uint4*)&y2b[(size_t)(bp[k] & 0x3FFFFu) * 4u];
            a0 += blo(v.x); a1 += bhi(v.x); a2 += blo(v.y); a3 += bhi(v.y);
            a4 += blo(v.z); a5 += bhi(v.z); a6 += blo(v.w); a7 += bhi(v.w);
        }
    }
    float inv = 1.0f / fmaxf(cntf[g], 1.0f);
    float h2v[8];
    float s8[8] = {a0, a1, a2, a3, a4, a5, a6, a7};
#pragma unroll
    for (int j = 0; j < 8; j++) {
        float v = s8[j] * inv + sb[j] + z2h2[(size_t)g * 8 + j];
        h2v[j] = lrelu(v);
        z2h2[(size_t)g * 8 + j] = h2v[j];
    }
    float y[4];
#pragma unroll
    for (int k = 0; k < 4; k++) {
        float acc = 0.0f;
#pragma unroll
        for (int j = 0; j < 8; j++) acc += h2v[j] * sW3[j * 4 + k];
        y[k] = acc;
    }
    uint2 out;
    out.x = pk(y[0], y[1]); out.y = pk(y[2], y[3]);
    *(uint2*)&y3b[(size_t)g * 2u] = out;
}

// ---- Layer-3 gather + fused epilogue + pooling -------------------------
__global__ __launch_bounds__(256) void agg4pool_k(const unsigned* __restrict__ y3b,
                                                  const unsigned* __restrict__ binned,
                                                  const int* __restrict__ offs,
                                                  const float* __restrict__ cntf,
                                                  const float* __restrict__ h2,
                                                  const float* __restrict__ W3r,
                                                  const float* __restrict__ b3,
                                                  const int* __restrict__ batch,
                                                  float* __restrict__ pool,
                                                  float* __restrict__ gcnt) {
    __shared__ float sW[32], sb[4];
    __shared__ float lp[16][4];
    __shared__ float lc[16];
    __shared__ int sbase;
    if (threadIdx.x < 32) sW[threadIdx.x] = W3r[threadIdx.x];
    if (threadIdx.x < 4) sb[threadIdx.x] = b3[threadIdx.x];
    if (threadIdx.x < 16) {
        lc[threadIdx.x] = 0.0f;
        for (int k = 0; k < 4; k++) lp[threadIdx.x][k] = 0.0f;
    }
    int n0 = blockIdx.x * 256;
    if (threadIdx.x == 0) sbase = batch[n0 < N_NODES ? n0 : N_NODES - 1];
    __syncthreads();
    int g = n0 + threadIdx.x;
    if (g < N_NODES) {
        int bin = g >> BINB, f = g & (WIN - 1);
        float a0 = 0, a1 = 0, a2 = 0, a3 = 0;
#pragma unroll
        for (int q = 0; q < 4; q++) {
            int sub = (bin << 2) | q;
            const int* o = offs + (size_t)sub * 513;
            int s = o[f], e = o[f + 1];
            const unsigned* bp = binned + (size_t)sub * CAPQ;
            int k = s;
            for (; k + 4 <= e; k += 4) {
                unsigned w0 = bp[k], w1 = bp[k + 1], w2 = bp[k + 2], w3 = bp[k + 3];
                uint2 v0 = *(const uint2*)&y3b[(size_t)(w0 & 0x3FFFFu) * 2u];
                uint2 v1 = *(const uint2*)&y3b[(size_t)(w1 & 0x3FFFFu) * 2u];
                uint2 v2 = *(const uint2*)&y3b[(size_t)(w2 & 0x3FFFFu) * 2u];
                uint2 v3 = *(const uint2*)&y3b[(size_t)(w3 & 0x3FFFFu) * 2u];
                a0 += blo(v0.x) + blo(v1.x) + blo(v2.x) + blo(v3.x);
                a1 += bhi(v0.x) + bhi(v1.x) + bhi(v2.x) + bhi(v3.x);
                a2 += blo(v0.y) + blo(v1.y) + blo(v2.y) + blo(v3.y);
                a3 += bhi(v0.y) + bhi(v1.y) + bhi(v2.y) + bhi(v3.y);
            }
            for (; k < e; k++) {
                uint2 v = *(const uint2*)&y3b[(size_t)(bp[k] & 0x3FFFFu) * 2u];
                a0 += blo(v.x); a1 += bhi(v.x); a2 += blo(v.y); a3 += bhi(v.y);
            }
        }
        float inv = 1.0f / fmaxf(cntf[g], 1.0f);
        float s4[4] = {a0, a1, a2, a3};
        float h2v[8];
#pragma unroll
        for (int j = 0; j < 8; j++) h2v[j] = h2[(size_t)g * 8 + j];
        int b = batch[g];
        int off = b - sbase;
        bool local = (off >= 0 && off < 16);
#pragma unroll
        for (int k = 0; k < 4; k++) {
            float z = 0.0f;
#pragma unroll
            for (int j = 0; j < 8; j++) z += h2v[j] * sW[j * 4 + k];
            float v = s4[k] * inv + sb[k] + z;
            if (local) atomicAdd(&lp[off][k], v);
            else atomicAdd(&pool[b * 4 + k], v);
        }
        if (local) atomicAdd(&lc[off], 1.0f);
        else atomicAdd(&gcnt[b], 1.0f);
    }
    __syncthreads();
    if (threadIdx.x < 16) {
        int b = sbase + threadIdx.x;
        float c = lc[threadIdx.x];
        if (c > 0.0f && b < N_GRAPHS) {
            atomicAdd(&gcnt[b], c);
            for (int k = 0; k < 4; k++) atomicAdd(&pool[b * 4 + k], lp[threadIdx.x][k]);
        }
    }
}

__global__ __launch_bounds__(256) void final_k(const float* __restrict__ pool,
                                               const float* __restrict__ gcnt,
                                               const float* __restrict__ Wc,
                                               const float* __restrict__ bc,
                                               float* __restrict__ out) {
    int g = blockIdx.x * blockDim.x + threadIdx.x;
    if (g >= N_GRAPHS) return;
    float inv = 1.0f / fmaxf(gcnt[g], 1.0f);
    float acc = bc[0];
#pragma unroll
    for (int k = 0; k < 4; k++) {
        float ap = pool[g * 4 + k];
        acc += ap * inv * Wc[k] + ap * Wc[4 + k];
    }
    out[g] = acc;
}

extern "C" void kernel_launch(void* const* d_in, const int* in_sizes, int n_in,
                              void* d_out, int out_size, void* d_ws, size_t ws_size,
                              hipStream_t stream) {
    const float* x = (const float*)d_in[0];
    const int* ei = (const int*)d_in[1];
    const int* src = ei;
    const int* dst = ei + N_EDGES;
    const int* batch = (const int*)d_in[2];
    const float* W1l = (const float*)d_in[3];
    const float* b1 = (const float*)d_in[4];
    const float* W1r = (const float*)d_in[5];
    const float* W2l = (const float*)d_in[6];
    const float* b2 = (const float*)d_in[7];
    const float* W2r = (const float*)d_in[8];
    const float* W3l = (const float*)d_in[9];
    const float* b3 = (const float*)d_in[10];
    const float* W3r = (const float*)d_in[11];
    const float* Wc = (const float*)d_in[12];
    const float* bc = (const float*)d_in[13];
    float* out = (float*)d_out;

    const size_t N = N_NODES;
    unsigned* binned = (unsigned*)d_ws;                 // NSUB*CAPQ u32 ~= 20 MB
    int* qcnt = (int*)(binned + (size_t)NSUB * CAPQ);   // 2048 ints
    int* offs = qcnt + 2048;                            // NSUB*513 ints ~= 4 MB
    float* fbase = (float*)(offs + (size_t)NSUB * 513);
    float* agg = fbase;                         // 13N floats
    float* cntf = fbase + 13 * N;               // N
    float* z2 = cntf + N;                       // 8N (becomes h2 in place)
    unsigned* x16b = (unsigned*)(z2 + 8 * N);   // 8N u32
    unsigned* y2b = x16b + 8 * N;               // 4N u32
    unsigned* y3b = y2b + 4 * N;                // 2N u32
    float* pool = (float*)(y3b + 2 * N);        // 2048 (gcnt follows)
    float* gcnt = pool + N_GRAPHS * 4;          // 512

    const int TPB = 256;
    const int NB = (N_NODES + TPB - 1) / TPB;

    // 7 dispatches; zeroing folded into producers.
    pack_x<<<(N_NODES * 8 + TPB - 1) / TPB, TPB, 0, stream>>>(x, x16b, qcnt);
    partition_k<<<PART_BLOCKS, 1024, 0, stream>>>(src, dst, qcnt, binned);
    sortagg_k<<<NBINS, 1024, 0, stream>>>(x16b, binned, qcnt, offs, cntf, agg);
    fused1<<<NB, TPB, 0, stream>>>(agg, x, cntf, W1l, b1, W1r, W2l, W2r, y2b, z2);
    agg8f_k<<<NB, TPB, 0, stream>>>(y2b, binned, offs, cntf, b2, W3l, z2, y3b, pool);
    agg4pool_k<<<NB, TPB, 0, stream>>>(y3b, binned, offs, cntf, z2, W3r, b3, batch, pool, gcnt);
    final_k<<<2, TPB, 0, stream>>>(pool, gcnt, Wc, bc, out);
}